// Round 11
// baseline (682.266 us; speedup 1.0000x reference)
//
#include <hip/hip_runtime.h>
#include <hip/hip_fp16.h>
#include <hip/hip_cooperative_groups.h>

namespace cg = cooperative_groups;

#define NVOX 65536
#define KVOL 125
#define NPAIR 1048576
#define CAP 48            // per-voxel bin capacity; counts ~ Poisson(16)
#define FUSED_BLOCKS 1024 // 4 blocks/CU x 256 CU, LDS-limited co-residency
#define QKV_BLOCKS 768
#define FILL_BLOCKS 2048
#define MERGED_BLOCKS (QKV_BLOCKS + FILL_BLOCKS)   // fallback path (R9)
#define GATH_BLOCKS 1024

typedef _Float16 half8 __attribute__((ext_vector_type(8)));
typedef float f32x4 __attribute__((ext_vector_type(4)));

// ---------------------------------------------------------------------------
// pair helpers (R9, unchanged): permuted pairlist -> uint4 queue reads
// ---------------------------------------------------------------------------
__device__ __forceinline__ void pair_accum(
    unsigned pk, unsigned kk, uint2 vv, const __half* npos_s, int cc,
    const float4& a4, const float4& a4s, float4& ac)
{
    const int kidx = (int)(pk & 127u);
    const __half2* np = (const __half2*)&npos_s[kidx * 64 + cc];
    const float2 c01 = __half22float2(np[0]);
    const float2 c23 = __half22float2(np[1]);
    const int ki = (int)kk;
    const float k0 = (float)(signed char)(ki);
    const float k1 = (float)(signed char)(ki >> 8);
    const float k2 = (float)(signed char)(ki >> 16);
    const float k3 = (float)(ki >> 24);
    float pdot = a4s.x * k0 + a4s.y * k1 + a4s.z * k2 + a4s.w * k3
               + a4.x * c01.x + a4.y * c01.y + a4.z * c23.x + a4.w * c23.y;
    pdot += __shfl_xor(pdot, 1);
    pdot += __shfl_xor(pdot, 2);
    const float2 v01 = __half22float2(*(const __half2*)&vv.x);
    const float2 v23 = __half22float2(*(const __half2*)&vv.y);
    ac.x += pdot * v01.x; ac.y += pdot * v01.y;
    ac.z += pdot * v23.x; ac.w += pdot * v23.y;
}

__device__ __forceinline__ void quad_accum(
    uint4 u, const signed char* __restrict__ ktab, const __half* __restrict__ vtab,
    const __half* npos_s, int cc, const float4& a4, const float4& a4s, float4& ac)
{
    const unsigned kk0 = *(const unsigned*)(ktab + (size_t)(u.x >> 7) * 64 + cc);
    const unsigned kk1 = *(const unsigned*)(ktab + (size_t)(u.y >> 7) * 64 + cc);
    const unsigned kk2 = *(const unsigned*)(ktab + (size_t)(u.z >> 7) * 64 + cc);
    const unsigned kk3 = *(const unsigned*)(ktab + (size_t)(u.w >> 7) * 64 + cc);
    const uint2 vv0 = *(const uint2*)(vtab + (size_t)(u.x >> 7) * 64 + cc);
    const uint2 vv1 = *(const uint2*)(vtab + (size_t)(u.y >> 7) * 64 + cc);
    const uint2 vv2 = *(const uint2*)(vtab + (size_t)(u.z >> 7) * 64 + cc);
    const uint2 vv3 = *(const uint2*)(vtab + (size_t)(u.w >> 7) * 64 + cc);
    pair_accum(u.x, kk0, vv0, npos_s, cc, a4, a4s, ac);
    pair_accum(u.y, kk1, vv1, npos_s, cc, a4, a4s, ac);
    pair_accum(u.z, kk2, vv2, npos_s, cc, a4, a4s, ac);
    pair_accum(u.w, kk3, vv3, npos_s, cc, a4, a4s, ac);
}

__device__ __forceinline__ void tail_accum(
    uint4 u, int r, const signed char* __restrict__ ktab, const __half* __restrict__ vtab,
    const __half* npos_s, int cc, const float4& a4, const float4& a4s, float4& ac)
{
    if (r > 0) {
        const unsigned kk = *(const unsigned*)(ktab + (size_t)(u.x >> 7) * 64 + cc);
        const uint2 vv = *(const uint2*)(vtab + (size_t)(u.x >> 7) * 64 + cc);
        pair_accum(u.x, kk, vv, npos_s, cc, a4, a4s, ac);
    }
    if (r > 1) {
        const unsigned kk = *(const unsigned*)(ktab + (size_t)(u.y >> 7) * 64 + cc);
        const uint2 vv = *(const uint2*)(vtab + (size_t)(u.y >> 7) * 64 + cc);
        pair_accum(u.y, kk, vv, npos_s, cc, a4, a4s, ac);
    }
    if (r > 2) {
        const unsigned kk = *(const unsigned*)(ktab + (size_t)(u.z >> 7) * 64 + cc);
        const uint2 vv = *(const uint2*)(vtab + (size_t)(u.z >> 7) * 64 + cc);
        pair_accum(u.z, kk, vv, npos_s, cc, a4, a4s, ac);
    }
}

// ---------------------------------------------------------------------------
// shared phase bodies (used by both the fused kernel and the fallback kernels)
// ---------------------------------------------------------------------------
__device__ __forceinline__ void qkv_body(
    _Float16* wth, int tid, int lane, int nb_base_wave,
    const float* __restrict__ x,
    const float* __restrict__ Wq, const float* __restrict__ bq,
    const float* __restrict__ Wk, const float* __restrict__ bk,
    const float* __restrict__ Wv, const float* __restrict__ bv,
    __half* __restrict__ nqh, signed char* __restrict__ ktab,
    __half* __restrict__ vtab, int tiles_stride, int do_loop)
{
    for (int idx = tid; idx < 3 * 4096; idx += 256) {
        const int m = idx >> 12;
        const int r = idx & 4095;
        const int k = r >> 6;
        const int c = r & 63;
        const float wv = (m == 0 ? Wq : (m == 1 ? Wk : Wv))[k * 64 + c];
        wth[(m * 64 + c) * 72 + k] = (_Float16)wv;
    }
    __syncthreads();

    const int lr = lane & 15;
    const int kg = lane >> 4;

    for (int tile = nb_base_wave; tile < 4096; tile += tiles_stride) {
        const int nb = tile << 4;
        half8 af[2];
        #pragma unroll
        for (int ks = 0; ks < 2; ++ks) {
            const float4 xa = *(const float4*)&x[(size_t)(nb + lr) * 64 + ks * 32 + kg * 8];
            const float4 xb = *(const float4*)&x[(size_t)(nb + lr) * 64 + ks * 32 + kg * 8 + 4];
            half8 t;
            t[0] = (_Float16)xa.x; t[1] = (_Float16)xa.y;
            t[2] = (_Float16)xa.z; t[3] = (_Float16)xa.w;
            t[4] = (_Float16)xb.x; t[5] = (_Float16)xb.y;
            t[6] = (_Float16)xb.z; t[7] = (_Float16)xb.w;
            af[ks] = t;
        }
        #pragma unroll
        for (int m = 0; m < 3; ++m) {
            const float* bp = (m == 0 ? bq : (m == 1 ? bk : bv));
            #pragma unroll
            for (int t = 0; t < 4; ++t) {
                f32x4 c = {0.f, 0.f, 0.f, 0.f};
                #pragma unroll
                for (int ks = 0; ks < 2; ++ks) {
                    const half8 bf = *(const half8*)&wth[(m * 64 + t * 16 + lr) * 72 + ks * 32 + kg * 8];
                    c = __builtin_amdgcn_mfma_f32_16x16x32_f16(af[ks], bf, c, 0, 0, 0);
                }
                const float bias = bp[t * 16 + lr];
                if (m < 2) {
                    #pragma unroll
                    for (int r = 0; r < 4; ++r) {
                        const float av = c[r] + bias;
                        float s = av * av;
                        s += __shfl_xor(s, 1); s += __shfl_xor(s, 2);
                        s += __shfl_xor(s, 4); s += __shfl_xor(s, 8);
                        const float inv = av / fmaxf(sqrtf(s), 1e-12f);
                        const size_t o = (size_t)(nb + kg * 4 + r) * 64 + t * 16 + lr;
                        if (m == 0) nqh[o] = __float2half(inv);
                        else        ktab[o] = (signed char)__float2int_rn(inv * 127.f);
                    }
                } else {
                    #pragma unroll
                    for (int r = 0; r < 4; ++r) {
                        const size_t o = (size_t)(nb + kg * 4 + r) * 64 + t * 16 + lr;
                        vtab[o] = __float2half(c[r] + bias);
                    }
                }
            }
        }
        if (!do_loop) break;
    }
}

__device__ __forceinline__ void gather_body(
    float* wo_s, __half* npos_s, float* ms, int tid,
    const int* __restrict__ cursor, const unsigned int* __restrict__ pairlist,
    const __half* __restrict__ nqh, const signed char* __restrict__ ktab,
    const __half* __restrict__ vtab, const __half* __restrict__ nposh,
    const float* __restrict__ Wo, const float* __restrict__ bo,
    const float* __restrict__ x, float* __restrict__ out, int bid)
{
    for (int i = tid; i < 1024; i += 256) ((float4*)wo_s)[i] = ((const float4*)Wo)[i];
    for (int i = tid; i < 1000; i += 256) ((uint4*)npos_s)[i] = ((const uint4*)nposh)[i];
    __syncthreads();

    const int lane = tid & 63;
    const int wid  = tid >> 6;
    const int l    = lane & 15;
    const int pg   = lane >> 4;
    const int cc   = l * 4;
    const int gw   = bid * 4 + wid;   // 4096 waves
    const float4 bo4 = *(const float4*)&bo[cc];

    for (int nb = gw * 4; nb < NVOX; nb += GATH_BLOCKS * 16) {
        #pragma unroll
        for (int v = 0; v < 4; ++v) {
            const int n = nb + v;
            const uint2 qp = *(const uint2*)(nqh + (size_t)n * 64 + cc);
            const float2 q01 = __half22float2(*(const __half2*)&qp.x);
            const float2 q23 = __half22float2(*(const __half2*)&qp.y);
            const float4 a4 = make_float4(q01.x, q01.y, q23.x, q23.y);
            const float4 a4s = make_float4(a4.x * (1.f / 127.f), a4.y * (1.f / 127.f),
                                           a4.z * (1.f / 127.f), a4.w * (1.f / 127.f));
            const int cnt = min(cursor[n], CAP);
            const int m = (cnt > pg) ? ((cnt - pg + 3) >> 2) : 0;
            const uint4* pb = (const uint4*)(pairlist + (size_t)n * CAP + pg * 12);
            const uint4 u0 = pb[0];
            const uint4 u1 = pb[1];
            const uint4 u2 = pb[2];
            float4 acc = make_float4(0.f, 0.f, 0.f, 0.f);
            int rem = m;
            if (rem >= 4) { quad_accum(u0, ktab, vtab, npos_s, cc, a4, a4s, acc); rem -= 4; }
            else          { tail_accum(u0, rem, ktab, vtab, npos_s, cc, a4, a4s, acc); rem = 0; }
            if (rem >= 4) { quad_accum(u1, ktab, vtab, npos_s, cc, a4, a4s, acc); rem -= 4; }
            else if (rem > 0) { tail_accum(u1, rem, ktab, vtab, npos_s, cc, a4, a4s, acc); rem = 0; }
            if (rem >= 4) { quad_accum(u2, ktab, vtab, npos_s, cc, a4, a4s, acc); rem -= 4; }
            else if (rem > 0) { tail_accum(u2, rem, ktab, vtab, npos_s, cc, a4, a4s, acc); rem = 0; }
            acc.x += __shfl_xor(acc.x, 16); acc.y += __shfl_xor(acc.y, 16);
            acc.z += __shfl_xor(acc.z, 16); acc.w += __shfl_xor(acc.w, 16);
            acc.x += __shfl_xor(acc.x, 32); acc.y += __shfl_xor(acc.y, 32);
            acc.z += __shfl_xor(acc.z, 32); acc.w += __shfl_xor(acc.w, 32);
            if (pg == 0) *(float4*)&ms[(wid * 4 + v) * 64 + cc] = acc;
        }
        __syncthreads();
        float4 o4[4];
        #pragma unroll
        for (int v = 0; v < 4; ++v) o4[v] = make_float4(0.f, 0.f, 0.f, 0.f);
        #pragma unroll
        for (int ib = 0; ib < 4; ++ib) {
            float4 mq[4];
            #pragma unroll
            for (int v = 0; v < 4; ++v)
                mq[v] = *(const float4*)&ms[(wid * 4 + v) * 64 + pg * 16 + ib * 4];
            #pragma unroll
            for (int tt = 0; tt < 4; ++tt) {
                const int j = pg * 16 + ib * 4 + tt;
                const float4 w4 = *(const float4*)&wo_s[j * 64 + cc];
                #pragma unroll
                for (int v = 0; v < 4; ++v) {
                    const float m = (tt == 0 ? mq[v].x : tt == 1 ? mq[v].y :
                                     tt == 2 ? mq[v].z : mq[v].w);
                    o4[v].x += m * w4.x; o4[v].y += m * w4.y;
                    o4[v].z += m * w4.z; o4[v].w += m * w4.w;
                }
            }
        }
        #pragma unroll
        for (int v = 0; v < 4; ++v) {
            o4[v].x += __shfl_xor(o4[v].x, 16); o4[v].y += __shfl_xor(o4[v].y, 16);
            o4[v].z += __shfl_xor(o4[v].z, 16); o4[v].w += __shfl_xor(o4[v].w, 16);
            o4[v].x += __shfl_xor(o4[v].x, 32); o4[v].y += __shfl_xor(o4[v].y, 32);
            o4[v].z += __shfl_xor(o4[v].z, 32); o4[v].w += __shfl_xor(o4[v].w, 32);
        }
        if (pg == 0) {
            #pragma unroll
            for (int v = 0; v < 4; ++v) {
                const float4 xr = *(const float4*)&x[(size_t)(nb + v) * 64 + cc];
                float4 r;
                r.x = o4[v].x + bo4.x + xr.x;
                r.y = o4[v].y + bo4.y + xr.y;
                r.z = o4[v].z + bo4.z + xr.z;
                r.w = o4[v].w + bo4.w + xr.w;
                *(float4*)&out[(size_t)(nb + v) * 64 + cc] = r;
            }
        }
        __syncthreads();
    }
}

// ---------------------------------------------------------------------------
// R11 cooperative kernel: R10 phases + SYMMETRIC agent-scope fences at every
// grid.sync (release=wbL2 before, acquire=invL2 after). R10's failure: (1) no
// fence after phase-0 cursor zero-stores -> atomics RMW'd stale HBM; (2) no
// acquire after phase1->2 sync -> zeroing XCDs read their clean-stale cursor
// lines. Per-XCD L2s are non-coherent; fences ARE the G16 device-scope ops.
// ---------------------------------------------------------------------------
__global__ __launch_bounds__(256, 4) void fused_kernel(
    const float* __restrict__ x,
    const float* __restrict__ Wq, const float* __restrict__ bq,
    const float* __restrict__ Wk, const float* __restrict__ bk,
    const float* __restrict__ Wv, const float* __restrict__ bv,
    const float* __restrict__ Wo, const float* __restrict__ bo,
    const float* __restrict__ pos, const int* __restrict__ kq_map,
    __half* __restrict__ nqh, signed char* __restrict__ ktab,
    __half* __restrict__ vtab, __half* __restrict__ nposh,
    int* __restrict__ cursor, unsigned int* __restrict__ pairlist,
    float* __restrict__ out)
{
    __shared__ __align__(16) char smem[36864];
    const int tid  = threadIdx.x;
    const int bid  = blockIdx.x;
    const int lane = tid & 63;
    const int wid  = tid >> 6;
    cg::grid_group grid = cg::this_grid();

    // ---------------- phase 0: zero cursor ----------------
    {
        const int zi = bid * 256 + tid;
        if (zi < NVOX / 4) ((int4*)cursor)[zi] = make_int4(0, 0, 0, 0);
    }
    __threadfence();           // release: write back dirty zero-lines (wbL2)
    grid.sync();
    __threadfence();           // acquire: invalidate stale lines (invL2)

    // ---------------- phase 1a: qkv MFMA GEMM ----------------
    {
        _Float16* wth = (_Float16*)smem;
        if (bid < KVOL && wid == 0) {      // posnorm piggyback
            const float pv = pos[bid * 64 + lane];
            float s = pv * pv;
            #pragma unroll
            for (int m = 1; m <= 8; m <<= 1) s += __shfl_xor(s, m);
            nposh[bid * 64 + lane] = __float2half(pv / fmaxf(sqrtf(s), 1e-12f));
        }
        qkv_body(wth, tid, lane, bid * 4 + wid, x, Wq, bq, Wk, bk, Wv, bv,
                 nqh, ktab, vtab, 4096, 0);   // exactly 1 tile per wave
    }

    // ---------------- phase 1b: fill (4 pairs/thread) ----------------
    {
        const int gt = bid * 256 + tid;            // 0..262143
        #pragma unroll
        for (int kq4 = 0; kq4 < 4; ++kq4) {
            const int p = gt + kq4 * 262144;
            const unsigned kk = (unsigned)kq_map[p];
            const int oo = kq_map[NPAIR + p];
            const int r = atomicAdd(&cursor[oo], 1);
            const unsigned ii = kk / 125u;
            if (r < CAP) pairlist[(size_t)oo * CAP + ((r & 3) * 12 + (r >> 2))]
                            = (ii << 7) | (kk - ii * 125u);
        }
    }
    __threadfence();           // release: nqh/ktab/vtab/pairlist -> HBM
    grid.sync();
    __threadfence();           // acquire: drop stale cursor/table lines

    // ---------------- phase 2: gather + attention + Wo + residual ----------------
    {
        float*  wo_s   = (float*)smem;
        __half* npos_s = (__half*)(smem + 16384);
        float*  ms     = (float*)(smem + 32768);
        gather_body(wo_s, npos_s, ms, tid, cursor, pairlist, nqh, ktab, vtab,
                    nposh, Wo, bo, x, out, bid);
    }
}

// ---------------------------------------------------------------------------
// Fallback path: EXACT R9 three-kernel pipeline (proven 222.7 us, passed).
// ---------------------------------------------------------------------------
__global__ __launch_bounds__(256) void zero_cursor_kernel(int4* __restrict__ c4)
{
    c4[blockIdx.x * 256 + threadIdx.x] = make_int4(0, 0, 0, 0);
}

__global__ __launch_bounds__(256, 3) void qkv_fill_kernel(
    const float* __restrict__ x,
    const float* __restrict__ Wq, const float* __restrict__ bq,
    const float* __restrict__ Wk, const float* __restrict__ bk,
    const float* __restrict__ Wv, const float* __restrict__ bv,
    __half* __restrict__ nqh, signed char* __restrict__ ktab,
    __half* __restrict__ vtab,
    const float* __restrict__ pos, const int* __restrict__ kq_map,
    __half* __restrict__ nposh, int* __restrict__ cursor,
    unsigned int* __restrict__ pairlist)
{
    __shared__ _Float16 wth[3 * 64 * 72];
    const int tid  = threadIdx.x;
    const int lane = tid & 63;
    const int wid  = tid >> 6;
    const int grp  = blockIdx.x / 11;
    const int sub  = blockIdx.x - grp * 11;

    if (sub >= 3) {
        const int fb = grp * 8 + (sub - 3);
        if (fb < KVOL && wid == 0) {
            const float pv = pos[fb * 64 + lane];
            float s = pv * pv;
            #pragma unroll
            for (int m = 1; m <= 8; m <<= 1) s += __shfl_xor(s, m);
            nposh[fb * 64 + lane] = __float2half(pv / fmaxf(sqrtf(s), 1e-12f));
        }
        const int gtid = fb * 256 + tid;
        const int p0 = gtid;
        const int p1 = gtid + 524288;
        const unsigned k0 = (unsigned)kq_map[p0];
        const unsigned k1 = (unsigned)kq_map[p1];
        const int o0 = kq_map[NPAIR + p0];
        const int o1 = kq_map[NPAIR + p1];
        const int r0 = atomicAdd(&cursor[o0], 1);
        const int r1 = atomicAdd(&cursor[o1], 1);
        const unsigned i0 = k0 / 125u, i1 = k1 / 125u;
        if (r0 < CAP) pairlist[(size_t)o0 * CAP + ((r0 & 3) * 12 + (r0 >> 2))]
                        = (i0 << 7) | (k0 - i0 * 125u);
        if (r1 < CAP) pairlist[(size_t)o1 * CAP + ((r1 & 3) * 12 + (r1 >> 2))]
                        = (i1 << 7) | (k1 - i1 * 125u);
        return;
    }

    const int qb = grp * 3 + sub;
    qkv_body(wth, tid, lane, qb * 4 + wid, x, Wq, bq, Wk, bk, Wv, bv,
             nqh, ktab, vtab, 3072, 1);
}

__global__ __launch_bounds__(256, 4) void gather_out_kernel(
    const int* __restrict__ cursor, const unsigned int* __restrict__ pairlist,
    const __half* __restrict__ nqh, const signed char* __restrict__ ktab,
    const __half* __restrict__ vtab, const __half* __restrict__ nposh,
    const float* __restrict__ Wo, const float* __restrict__ bo,
    const float* __restrict__ x, float* __restrict__ out)
{
    __shared__ __align__(16) char smem[36864];
    gather_body((float*)smem, (__half*)(smem + 16384), (float*)(smem + 32768),
                threadIdx.x, cursor, pairlist, nqh, ktab, vtab, nposh,
                Wo, bo, x, out, blockIdx.x);
}

// ---------------------------------------------------------------------------
extern "C" void kernel_launch(void* const* d_in, const int* in_sizes, int n_in,
                              void* d_out, int out_size, void* d_ws, size_t ws_size,
                              hipStream_t stream) {
    const float* x   = (const float*)d_in[0];
    const float* Wq  = (const float*)d_in[1];
    const float* bq  = (const float*)d_in[2];
    const float* Wk  = (const float*)d_in[3];
    const float* bk  = (const float*)d_in[4];
    const float* Wv  = (const float*)d_in[5];
    const float* bv  = (const float*)d_in[6];
    const float* Wo  = (const float*)d_in[7];
    const float* bo  = (const float*)d_in[8];
    const float* pos = (const float*)d_in[9];
    const int*   kq  = (const int*)d_in[10];

    char* w = (char*)d_ws;
    __half*       nqh      = (__half*)w;       w += (size_t)NVOX * 64 * 2;    // 8 MB
    __half*       vtab     = (__half*)w;       w += (size_t)NVOX * 64 * 2;    // 8 MB
    signed char*  ktab     = (signed char*)w;  w += (size_t)NVOX * 64;        // 4 MB
    unsigned int* pairlist = (unsigned int*)w; w += (size_t)NVOX * CAP * 4;   // 12 MB
    int*          cursor   = (int*)w;          w += (size_t)NVOX * 4;         // 256 KB
    __half*       nposh    = (__half*)w;       w += 16384;                    // 16 KB
    float*        outp     = (float*)d_out;

    void* args[] = { (void*)&x, (void*)&Wq, (void*)&bq, (void*)&Wk, (void*)&bk,
                     (void*)&Wv, (void*)&bv, (void*)&Wo, (void*)&bo, (void*)&pos,
                     (void*)&kq, (void*)&nqh, (void*)&ktab, (void*)&vtab,
                     (void*)&nposh, (void*)&cursor, (void*)&pairlist, (void*)&outp };
    hipError_t err = hipLaunchCooperativeKernel((const void*)fused_kernel,
                                                dim3(FUSED_BLOCKS), dim3(256),
                                                args, 0, stream);
    if (err != hipSuccess) {
        (void)hipGetLastError();   // clear sticky error; fall back to R9 path
        zero_cursor_kernel<<<64, 256, 0, stream>>>((int4*)cursor);
        qkv_fill_kernel<<<MERGED_BLOCKS, 256, 0, stream>>>(x, Wq, bq, Wk, bk, Wv, bv,
                                                           nqh, ktab, vtab,
                                                           pos, kq, nposh, cursor, pairlist);
        gather_out_kernel<<<GATH_BLOCKS, 256, 0, stream>>>(cursor, pairlist, nqh, ktab,
                                                           vtab, nposh, Wo, bo, x, outp);
    }
}

// Round 12
// 228.548 us; speedup vs baseline: 2.9852x; 2.9852x over previous
//
#include <hip/hip_runtime.h>
#include <hip/hip_fp16.h>

#define NVOX 65536
#define KVOL 125
#define NPAIR 1048576
#define CAP 48            // per-voxel bin capacity; counts ~ Poisson(16)
#define QKV_BLOCKS 768
#define FILL_BLOCKS 2048
#define MERGED_BLOCKS (QKV_BLOCKS + FILL_BLOCKS)   // 2816 = 256 groups * 11
#define GATH_BLOCKS 1024   // R6: more gather concurrency = L2 thrash; R11: coop/grid.sync dead (596us)

typedef _Float16 half8 __attribute__((ext_vector_type(8)));
typedef float f32x4 __attribute__((ext_vector_type(4)));

// ---------------------------------------------------------------------------
// cursor zeroing (must precede fill-role atomics; stream order guarantees it)
// ---------------------------------------------------------------------------
__global__ __launch_bounds__(256) void zero_cursor_kernel(int4* __restrict__ c4)
{
    c4[blockIdx.x * 256 + threadIdx.x] = make_int4(0, 0, 0, 0);
}

// ---------------------------------------------------------------------------
// FUSED qkv + fill — R9 structure (222.7 us best). qkv = MFMA GEMM; fill with
// permuted pairlist slots. R12 change: V is quantized to int8 with a
// PER-VOXEL scale (row absmax via the same 16-lane shfl_xor reduce used for
// q/k norms). vtab row: 128B -> 64B = half of gather's dominant random
// traffic. Scale table (256KB fp32) is L2-resident in gather.
// ---------------------------------------------------------------------------
__global__ __launch_bounds__(256, 3) void qkv_fill_kernel(
    const float* __restrict__ x,
    const float* __restrict__ Wq, const float* __restrict__ bq,
    const float* __restrict__ Wk, const float* __restrict__ bk,
    const float* __restrict__ Wv, const float* __restrict__ bv,
    __half* __restrict__ nqh, signed char* __restrict__ ktab,
    signed char* __restrict__ vtab, float* __restrict__ vscale,
    const float* __restrict__ pos, const int* __restrict__ kq_map,
    __half* __restrict__ nposh, int* __restrict__ cursor,
    unsigned int* __restrict__ pairlist)
{
    __shared__ _Float16 wth[3 * 64 * 72];   // qkv role only: W^T fp16 [m][c][k]
    const int tid  = threadIdx.x;
    const int lane = tid & 63;
    const int wid  = tid >> 6;
    const int grp  = blockIdx.x / 11;
    const int sub  = blockIdx.x - grp * 11;

    if (sub >= 3) {
        // ---------------- fill role (block id fb in [0, 2048)) ----------------
        const int fb = grp * 8 + (sub - 3);
        if (fb < KVOL && wid == 0) {
            const float pv = pos[fb * 64 + lane];
            float s = pv * pv;
            #pragma unroll
            for (int m = 1; m <= 8; m <<= 1) s += __shfl_xor(s, m);
            nposh[fb * 64 + lane] = __float2half(pv / fmaxf(sqrtf(s), 1e-12f));
        }
        const int gtid = fb * 256 + tid;            // 0..524287
        const int p0 = gtid;
        const int p1 = gtid + 524288;
        const unsigned k0 = (unsigned)kq_map[p0];
        const unsigned k1 = (unsigned)kq_map[p1];
        const int o0 = kq_map[NPAIR + p0];
        const int o1 = kq_map[NPAIR + p1];
        const int r0 = atomicAdd(&cursor[o0], 1);
        const int r1 = atomicAdd(&cursor[o1], 1);
        const unsigned i0 = k0 / 125u, i1 = k1 / 125u;
        // permuted slot: group-major layout for uint4 gather reads
        if (r0 < CAP) pairlist[(size_t)o0 * CAP + ((r0 & 3) * 12 + (r0 >> 2))]
                        = (i0 << 7) | (k0 - i0 * 125u);
        if (r1 < CAP) pairlist[(size_t)o1 * CAP + ((r1 & 3) * 12 + (r1 >> 2))]
                        = (i1 << 7) | (k1 - i1 * 125u);
        return;
    }

    // ---------------- qkv role (block id qb in [0, 768)) ----------------
    const int qb = grp * 3 + sub;
    for (int idx = tid; idx < 3 * 4096; idx += 256) {
        const int m = idx >> 12;
        const int r = idx & 4095;
        const int k = r >> 6;      // input channel (W row)
        const int c = r & 63;      // output channel (W col)
        const float wv = (m == 0 ? Wq : (m == 1 ? Wk : Wv))[k * 64 + c];
        wth[(m * 64 + c) * 72 + k] = (_Float16)wv;
    }
    __syncthreads();

    const int lr = lane & 15;   // A-row / C-col / B-col
    const int kg = lane >> 4;   // k-group of 8
    const int gw = qb * 4 + wid;       // 3072 waves, 4096 tiles of 16 voxels

    for (int tile = gw; tile < 4096; tile += 3072) {
        const int nb = tile << 4;
        half8 af[2];
        #pragma unroll
        for (int ks = 0; ks < 2; ++ks) {
            const float4 xa = *(const float4*)&x[(size_t)(nb + lr) * 64 + ks * 32 + kg * 8];
            const float4 xb = *(const float4*)&x[(size_t)(nb + lr) * 64 + ks * 32 + kg * 8 + 4];
            half8 t;
            t[0] = (_Float16)xa.x; t[1] = (_Float16)xa.y;
            t[2] = (_Float16)xa.z; t[3] = (_Float16)xa.w;
            t[4] = (_Float16)xb.x; t[5] = (_Float16)xb.y;
            t[6] = (_Float16)xb.z; t[7] = (_Float16)xb.w;
            af[ks] = t;
        }
        // ---- q and k: project, L2-normalize per head, store ----
        #pragma unroll
        for (int m = 0; m < 2; ++m) {
            const float* bp = (m == 0 ? bq : bk);
            #pragma unroll
            for (int t = 0; t < 4; ++t) {        // head / 16-col output tile
                f32x4 c = {0.f, 0.f, 0.f, 0.f};
                #pragma unroll
                for (int ks = 0; ks < 2; ++ks) {
                    const half8 bf = *(const half8*)&wth[(m * 64 + t * 16 + lr) * 72 + ks * 32 + kg * 8];
                    c = __builtin_amdgcn_mfma_f32_16x16x32_f16(af[ks], bf, c, 0, 0, 0);
                }
                const float bias = bp[t * 16 + lr];
                #pragma unroll
                for (int r = 0; r < 4; ++r) {
                    const float av = c[r] + bias;
                    float s = av * av;
                    s += __shfl_xor(s, 1); s += __shfl_xor(s, 2);
                    s += __shfl_xor(s, 4); s += __shfl_xor(s, 8);
                    const float inv = av / fmaxf(sqrtf(s), 1e-12f);
                    const size_t o = (size_t)(nb + kg * 4 + r) * 64 + t * 16 + lr;
                    if (m == 0) nqh[o] = __float2half(inv);
                    else        ktab[o] = (signed char)__float2int_rn(inv * 127.f);
                }
            }
        }
        // ---- v: project all 4 tiles, per-voxel-row int8 quantization ----
        {
            f32x4 cv[4];
            #pragma unroll
            for (int t = 0; t < 4; ++t) {
                f32x4 c = {0.f, 0.f, 0.f, 0.f};
                #pragma unroll
                for (int ks = 0; ks < 2; ++ks) {
                    const half8 bf = *(const half8*)&wth[(2 * 64 + t * 16 + lr) * 72 + ks * 32 + kg * 8];
                    c = __builtin_amdgcn_mfma_f32_16x16x32_f16(af[ks], bf, c, 0, 0, 0);
                }
                const float bias = bv[t * 16 + lr];
                #pragma unroll
                for (int r = 0; r < 4; ++r) cv[t][r] = c[r] + bias;
            }
            #pragma unroll
            for (int r = 0; r < 4; ++r) {
                float amax = fmaxf(fmaxf(fabsf(cv[0][r]), fabsf(cv[1][r])),
                                   fmaxf(fabsf(cv[2][r]), fabsf(cv[3][r])));
                amax = fmaxf(amax, __shfl_xor(amax, 1));
                amax = fmaxf(amax, __shfl_xor(amax, 2));
                amax = fmaxf(amax, __shfl_xor(amax, 4));
                amax = fmaxf(amax, __shfl_xor(amax, 8));
                const int n = nb + kg * 4 + r;
                const float sinv = (amax > 0.f) ? 127.f / amax : 0.f;
                #pragma unroll
                for (int t = 0; t < 4; ++t)
                    vtab[(size_t)n * 64 + t * 16 + lr] =
                        (signed char)__float2int_rn(cv[t][r] * sinv);
                if (lr == 0) vscale[n] = amax * (1.f / 127.f);
            }
        }
    }
}

// ---------------------------------------------------------------------------
// Gather + attention + Wo projection + residual. R9 frame; V now int8 rows
// (64B line) + per-voxel fp32 scale (256KB table, L2-resident broadcast).
// Per-pair random traffic 192B -> 128B.
// ---------------------------------------------------------------------------
__device__ __forceinline__ void pair_accum(
    unsigned pk, unsigned kk, unsigned vq, float vs, const __half* npos_s, int cc,
    const float4& a4, const float4& a4s, float4& ac)
{
    const int kidx = (int)(pk & 127u);
    const __half2* np = (const __half2*)&npos_s[kidx * 64 + cc];
    const float2 c01 = __half22float2(np[0]);
    const float2 c23 = __half22float2(np[1]);
    const int ki = (int)kk;
    const float k0 = (float)(signed char)(ki);
    const float k1 = (float)(signed char)(ki >> 8);
    const float k2 = (float)(signed char)(ki >> 16);
    const float k3 = (float)(ki >> 24);
    float pdot = a4s.x * k0 + a4s.y * k1 + a4s.z * k2 + a4s.w * k3
               + a4.x * c01.x + a4.y * c01.y + a4.z * c23.x + a4.w * c23.y;
    pdot += __shfl_xor(pdot, 1);
    pdot += __shfl_xor(pdot, 2);
    const float w = pdot * vs;
    const int vi = (int)vq;
    ac.x += w * (float)(signed char)(vi);
    ac.y += w * (float)(signed char)(vi >> 8);
    ac.z += w * (float)(signed char)(vi >> 16);
    ac.w += w * (float)(vi >> 24);
}

__device__ __forceinline__ void quad_accum(
    uint4 u, const signed char* __restrict__ ktab, const signed char* __restrict__ vtab,
    const float* __restrict__ vscale,
    const __half* npos_s, int cc, const float4& a4, const float4& a4s, float4& ac)
{
    const unsigned kk0 = *(const unsigned*)(ktab + (size_t)(u.x >> 7) * 64 + cc);
    const unsigned kk1 = *(const unsigned*)(ktab + (size_t)(u.y >> 7) * 64 + cc);
    const unsigned kk2 = *(const unsigned*)(ktab + (size_t)(u.z >> 7) * 64 + cc);
    const unsigned kk3 = *(const unsigned*)(ktab + (size_t)(u.w >> 7) * 64 + cc);
    const unsigned vq0 = *(const unsigned*)(vtab + (size_t)(u.x >> 7) * 64 + cc);
    const unsigned vq1 = *(const unsigned*)(vtab + (size_t)(u.y >> 7) * 64 + cc);
    const unsigned vq2 = *(const unsigned*)(vtab + (size_t)(u.z >> 7) * 64 + cc);
    const unsigned vq3 = *(const unsigned*)(vtab + (size_t)(u.w >> 7) * 64 + cc);
    const float vs0 = vscale[u.x >> 7];
    const float vs1 = vscale[u.y >> 7];
    const float vs2 = vscale[u.z >> 7];
    const float vs3 = vscale[u.w >> 7];
    pair_accum(u.x, kk0, vq0, vs0, npos_s, cc, a4, a4s, ac);
    pair_accum(u.y, kk1, vq1, vs1, npos_s, cc, a4, a4s, ac);
    pair_accum(u.z, kk2, vq2, vs2, npos_s, cc, a4, a4s, ac);
    pair_accum(u.w, kk3, vq3, vs3, npos_s, cc, a4, a4s, ac);
}

__device__ __forceinline__ void tail_accum(
    uint4 u, int r, const signed char* __restrict__ ktab, const signed char* __restrict__ vtab,
    const float* __restrict__ vscale,
    const __half* npos_s, int cc, const float4& a4, const float4& a4s, float4& ac)
{
    if (r > 0) {
        const unsigned kk = *(const unsigned*)(ktab + (size_t)(u.x >> 7) * 64 + cc);
        const unsigned vq = *(const unsigned*)(vtab + (size_t)(u.x >> 7) * 64 + cc);
        pair_accum(u.x, kk, vq, vscale[u.x >> 7], npos_s, cc, a4, a4s, ac);
    }
    if (r > 1) {
        const unsigned kk = *(const unsigned*)(ktab + (size_t)(u.y >> 7) * 64 + cc);
        const unsigned vq = *(const unsigned*)(vtab + (size_t)(u.y >> 7) * 64 + cc);
        pair_accum(u.y, kk, vq, vscale[u.y >> 7], npos_s, cc, a4, a4s, ac);
    }
    if (r > 2) {
        const unsigned kk = *(const unsigned*)(ktab + (size_t)(u.z >> 7) * 64 + cc);
        const unsigned vq = *(const unsigned*)(vtab + (size_t)(u.z >> 7) * 64 + cc);
        pair_accum(u.z, kk, vq, vscale[u.z >> 7], npos_s, cc, a4, a4s, ac);
    }
}

__global__ __launch_bounds__(256, 4) void gather_out_kernel(
    const int* __restrict__ cursor, const unsigned int* __restrict__ pairlist,
    const __half* __restrict__ nqh, const signed char* __restrict__ ktab,
    const signed char* __restrict__ vtab, const float* __restrict__ vscale,
    const __half* __restrict__ nposh,
    const float* __restrict__ Wo, const float* __restrict__ bo,
    const float* __restrict__ x, float* __restrict__ out)
{
    __shared__ float wo_s[4096];
    __shared__ __half npos_s[8192];
    __shared__ float ms[4][4][64];
    const int tid = threadIdx.x;
    for (int i = tid; i < 1024; i += 256) ((float4*)wo_s)[i] = ((const float4*)Wo)[i];
    for (int i = tid; i < 1000; i += 256) ((uint4*)npos_s)[i] = ((const uint4*)nposh)[i];
    __syncthreads();

    const int lane = tid & 63;
    const int wid  = tid >> 6;
    const int l    = lane & 15;
    const int pg   = lane >> 4;
    const int cc   = l * 4;
    const int gw   = blockIdx.x * 4 + wid;   // 4096 waves
    const float4 bo4 = *(const float4*)&bo[cc];

    for (int nb = gw * 4; nb < NVOX; nb += GATH_BLOCKS * 16) {
        // ---- pair phase: 4 voxels, register accumulation ----
        #pragma unroll
        for (int v = 0; v < 4; ++v) {
            const int n = nb + v;
            const uint2 qp = *(const uint2*)(nqh + (size_t)n * 64 + cc);
            const float2 q01 = __half22float2(*(const __half2*)&qp.x);
            const float2 q23 = __half22float2(*(const __half2*)&qp.y);
            const float4 a4 = make_float4(q01.x, q01.y, q23.x, q23.y);
            const float4 a4s = make_float4(a4.x * (1.f / 127.f), a4.y * (1.f / 127.f),
                                           a4.z * (1.f / 127.f), a4.w * (1.f / 127.f));
            const int cnt = min(cursor[n], CAP);
            const int m = (cnt > pg) ? ((cnt - pg + 3) >> 2) : 0;
            const uint4* pb = (const uint4*)(pairlist + (size_t)n * CAP + pg * 12);
            const uint4 u0 = pb[0];
            const uint4 u1 = pb[1];
            const uint4 u2 = pb[2];
            float4 acc = make_float4(0.f, 0.f, 0.f, 0.f);
            int rem = m;
            if (rem >= 4) { quad_accum(u0, ktab, vtab, vscale, npos_s, cc, a4, a4s, acc); rem -= 4; }
            else          { tail_accum(u0, rem, ktab, vtab, vscale, npos_s, cc, a4, a4s, acc); rem = 0; }
            if (rem >= 4) { quad_accum(u1, ktab, vtab, vscale, npos_s, cc, a4, a4s, acc); rem -= 4; }
            else if (rem > 0) { tail_accum(u1, rem, ktab, vtab, vscale, npos_s, cc, a4, a4s, acc); rem = 0; }
            if (rem >= 4) { quad_accum(u2, ktab, vtab, vscale, npos_s, cc, a4, a4s, acc); rem -= 4; }
            else if (rem > 0) { tail_accum(u2, rem, ktab, vtab, vscale, npos_s, cc, a4, a4s, acc); rem = 0; }
            acc.x += __shfl_xor(acc.x, 16); acc.y += __shfl_xor(acc.y, 16);
            acc.z += __shfl_xor(acc.z, 16); acc.w += __shfl_xor(acc.w, 16);
            acc.x += __shfl_xor(acc.x, 32); acc.y += __shfl_xor(acc.y, 32);
            acc.z += __shfl_xor(acc.z, 32); acc.w += __shfl_xor(acc.w, 32);
            if (pg == 0) *(float4*)&ms[wid][v][cc] = acc;
        }
        __syncthreads();
        // ---- epilogue: out = msg @ Wo + bo + x  (j split across quarters) ----
        float4 o4[4];
        #pragma unroll
        for (int v = 0; v < 4; ++v) o4[v] = make_float4(0.f, 0.f, 0.f, 0.f);
        #pragma unroll
        for (int ib = 0; ib < 4; ++ib) {
            float4 mq[4];
            #pragma unroll
            for (int v = 0; v < 4; ++v)
                mq[v] = *(const float4*)&ms[wid][v][pg * 16 + ib * 4];
            #pragma unroll
            for (int tt = 0; tt < 4; ++tt) {
                const int j = pg * 16 + ib * 4 + tt;
                const float4 w4 = *(const float4*)&wo_s[j * 64 + cc];
                #pragma unroll
                for (int v = 0; v < 4; ++v) {
                    const float m = (tt == 0 ? mq[v].x : tt == 1 ? mq[v].y :
                                     tt == 2 ? mq[v].z : mq[v].w);
                    o4[v].x += m * w4.x; o4[v].y += m * w4.y;
                    o4[v].z += m * w4.z; o4[v].w += m * w4.w;
                }
            }
        }
        #pragma unroll
        for (int v = 0; v < 4; ++v) {
            o4[v].x += __shfl_xor(o4[v].x, 16); o4[v].y += __shfl_xor(o4[v].y, 16);
            o4[v].z += __shfl_xor(o4[v].z, 16); o4[v].w += __shfl_xor(o4[v].w, 16);
            o4[v].x += __shfl_xor(o4[v].x, 32); o4[v].y += __shfl_xor(o4[v].y, 32);
            o4[v].z += __shfl_xor(o4[v].z, 32); o4[v].w += __shfl_xor(o4[v].w, 32);
        }
        if (pg == 0) {
            #pragma unroll
            for (int v = 0; v < 4; ++v) {
                const float4 xr = *(const float4*)&x[(size_t)(nb + v) * 64 + cc];
                float4 r;
                r.x = o4[v].x + bo4.x + xr.x;
                r.y = o4[v].y + bo4.y + xr.y;
                r.z = o4[v].z + bo4.z + xr.z;
                r.w = o4[v].w + bo4.w + xr.w;
                *(float4*)&out[(size_t)(nb + v) * 64 + cc] = r;
            }
        }
        __syncthreads();
    }
}

// ---------------------------------------------------------------------------
extern "C" void kernel_launch(void* const* d_in, const int* in_sizes, int n_in,
                              void* d_out, int out_size, void* d_ws, size_t ws_size,
                              hipStream_t stream) {
    const float* x   = (const float*)d_in[0];
    const float* Wq  = (const float*)d_in[1];
    const float* bq  = (const float*)d_in[2];
    const float* Wk  = (const float*)d_in[3];
    const float* bk  = (const float*)d_in[4];
    const float* Wv  = (const float*)d_in[5];
    const float* bv  = (const float*)d_in[6];
    const float* Wo  = (const float*)d_in[7];
    const float* bo  = (const float*)d_in[8];
    const float* pos = (const float*)d_in[9];
    const int*   kq  = (const int*)d_in[10];

    char* w = (char*)d_ws;
    __half*       nqh      = (__half*)w;       w += (size_t)NVOX * 64 * 2;    // 8 MB
    signed char*  vtab     = (signed char*)w;  w += (size_t)NVOX * 64;        // 4 MB
    signed char*  ktab     = (signed char*)w;  w += (size_t)NVOX * 64;        // 4 MB
    unsigned int* pairlist = (unsigned int*)w; w += (size_t)NVOX * CAP * 4;   // 12 MB
    int*          cursor   = (int*)w;          w += (size_t)NVOX * 4;         // 256 KB
    float*        vscale   = (float*)w;        w += (size_t)NVOX * 4;         // 256 KB
    __half*       nposh    = (__half*)w;       w += 16384;                    // 16 KB

    zero_cursor_kernel<<<64, 256, 0, stream>>>((int4*)cursor);
    qkv_fill_kernel<<<MERGED_BLOCKS, 256, 0, stream>>>(x, Wq, bq, Wk, bk, Wv, bv,
                                                       nqh, ktab, vtab, vscale,
                                                       pos, kq, nposh, cursor, pairlist);
    gather_out_kernel<<<GATH_BLOCKS, 256, 0, stream>>>(cursor, pairlist, nqh, ktab, vtab,
                                                       vscale, nposh, Wo, bo, x,
                                                       (float*)d_out);
}

// Round 13
// 221.965 us; speedup vs baseline: 3.0738x; 1.0297x over previous
//
#include <hip/hip_runtime.h>
#include <hip/hip_fp16.h>

#define NVOX 65536
#define KVOL 125
#define NPAIR 1048576
#define CAP 48            // per-voxel bin capacity; counts ~ Poisson(16)
#define QKV_BLOCKS 768
#define FILL_BLOCKS 2048
#define MERGED_BLOCKS (QKV_BLOCKS + FILL_BLOCKS)   // 2816 = 256 groups * 11
#define GATH_BLOCKS 1024   // R6: more gather concurrency = L2 thrash; R11: coop/grid.sync dead

typedef _Float16 half8 __attribute__((ext_vector_type(8)));
typedef float f32x4 __attribute__((ext_vector_type(4)));

// ---------------------------------------------------------------------------
// cursor zeroing (must precede fill-role atomics; stream order guarantees it)
// ---------------------------------------------------------------------------
__global__ __launch_bounds__(256) void zero_cursor_kernel(int4* __restrict__ c4)
{
    c4[blockIdx.x * 256 + threadIdx.x] = make_int4(0, 0, 0, 0);
}

// ---------------------------------------------------------------------------
// FUSED qkv + fill — R9/R12 structure. R13 change: K and V int8 rows are
// MERGED into one 128B line-aligned kvtab row (k = bytes 0..63, v = 64..127):
// gather's two random line-touches per pair become ONE, and the unique hot
// table drops to 8 MB. V int8 with per-voxel scale (R12, passed 0.078).
// ---------------------------------------------------------------------------
__global__ __launch_bounds__(256, 3) void qkv_fill_kernel(
    const float* __restrict__ x,
    const float* __restrict__ Wq, const float* __restrict__ bq,
    const float* __restrict__ Wk, const float* __restrict__ bk,
    const float* __restrict__ Wv, const float* __restrict__ bv,
    __half* __restrict__ nqh, signed char* __restrict__ kvtab,
    float* __restrict__ vscale,
    const float* __restrict__ pos, const int* __restrict__ kq_map,
    __half* __restrict__ nposh, int* __restrict__ cursor,
    unsigned int* __restrict__ pairlist)
{
    __shared__ _Float16 wth[3 * 64 * 72];   // qkv role only: W^T fp16 [m][c][k]
    const int tid  = threadIdx.x;
    const int lane = tid & 63;
    const int wid  = tid >> 6;
    const int grp  = blockIdx.x / 11;
    const int sub  = blockIdx.x - grp * 11;

    if (sub >= 3) {
        // ---------------- fill role (block id fb in [0, 2048)) ----------------
        const int fb = grp * 8 + (sub - 3);
        if (fb < KVOL && wid == 0) {
            const float pv = pos[fb * 64 + lane];
            float s = pv * pv;
            #pragma unroll
            for (int m = 1; m <= 8; m <<= 1) s += __shfl_xor(s, m);
            nposh[fb * 64 + lane] = __float2half(pv / fmaxf(sqrtf(s), 1e-12f));
        }
        const int gtid = fb * 256 + tid;            // 0..524287
        const int p0 = gtid;
        const int p1 = gtid + 524288;
        const unsigned k0 = (unsigned)kq_map[p0];
        const unsigned k1 = (unsigned)kq_map[p1];
        const int o0 = kq_map[NPAIR + p0];
        const int o1 = kq_map[NPAIR + p1];
        const int r0 = atomicAdd(&cursor[o0], 1);
        const int r1 = atomicAdd(&cursor[o1], 1);
        const unsigned i0 = k0 / 125u, i1 = k1 / 125u;
        // permuted slot: group-major layout for uint4 gather reads
        if (r0 < CAP) pairlist[(size_t)o0 * CAP + ((r0 & 3) * 12 + (r0 >> 2))]
                        = (i0 << 7) | (k0 - i0 * 125u);
        if (r1 < CAP) pairlist[(size_t)o1 * CAP + ((r1 & 3) * 12 + (r1 >> 2))]
                        = (i1 << 7) | (k1 - i1 * 125u);
        return;
    }

    // ---------------- qkv role (block id qb in [0, 768)) ----------------
    const int qb = grp * 3 + sub;
    for (int idx = tid; idx < 3 * 4096; idx += 256) {
        const int m = idx >> 12;
        const int r = idx & 4095;
        const int k = r >> 6;      // input channel (W row)
        const int c = r & 63;      // output channel (W col)
        const float wv = (m == 0 ? Wq : (m == 1 ? Wk : Wv))[k * 64 + c];
        wth[(m * 64 + c) * 72 + k] = (_Float16)wv;
    }
    __syncthreads();

    const int lr = lane & 15;   // A-row / C-col / B-col
    const int kg = lane >> 4;   // k-group of 8
    const int gw = qb * 4 + wid;       // 3072 waves, 4096 tiles of 16 voxels

    for (int tile = gw; tile < 4096; tile += 3072) {
        const int nb = tile << 4;
        half8 af[2];
        #pragma unroll
        for (int ks = 0; ks < 2; ++ks) {
            const float4 xa = *(const float4*)&x[(size_t)(nb + lr) * 64 + ks * 32 + kg * 8];
            const float4 xb = *(const float4*)&x[(size_t)(nb + lr) * 64 + ks * 32 + kg * 8 + 4];
            half8 t;
            t[0] = (_Float16)xa.x; t[1] = (_Float16)xa.y;
            t[2] = (_Float16)xa.z; t[3] = (_Float16)xa.w;
            t[4] = (_Float16)xb.x; t[5] = (_Float16)xb.y;
            t[6] = (_Float16)xb.z; t[7] = (_Float16)xb.w;
            af[ks] = t;
        }
        // ---- q and k: project, L2-normalize per head, store ----
        #pragma unroll
        for (int m = 0; m < 2; ++m) {
            const float* bp = (m == 0 ? bq : bk);
            #pragma unroll
            for (int t = 0; t < 4; ++t) {        // head / 16-col output tile
                f32x4 c = {0.f, 0.f, 0.f, 0.f};
                #pragma unroll
                for (int ks = 0; ks < 2; ++ks) {
                    const half8 bf = *(const half8*)&wth[(m * 64 + t * 16 + lr) * 72 + ks * 32 + kg * 8];
                    c = __builtin_amdgcn_mfma_f32_16x16x32_f16(af[ks], bf, c, 0, 0, 0);
                }
                const float bias = bp[t * 16 + lr];
                #pragma unroll
                for (int r = 0; r < 4; ++r) {
                    const float av = c[r] + bias;
                    float s = av * av;
                    s += __shfl_xor(s, 1); s += __shfl_xor(s, 2);
                    s += __shfl_xor(s, 4); s += __shfl_xor(s, 8);
                    const float inv = av / fmaxf(sqrtf(s), 1e-12f);
                    const int n = nb + kg * 4 + r;
                    if (m == 0) nqh[(size_t)n * 64 + t * 16 + lr] = __float2half(inv);
                    else        kvtab[(size_t)n * 128 + t * 16 + lr] =
                                    (signed char)__float2int_rn(inv * 127.f);
                }
            }
        }
        // ---- v: project all 4 tiles, per-voxel-row int8 quantization ----
        {
            f32x4 cv[4];
            #pragma unroll
            for (int t = 0; t < 4; ++t) {
                f32x4 c = {0.f, 0.f, 0.f, 0.f};
                #pragma unroll
                for (int ks = 0; ks < 2; ++ks) {
                    const half8 bf = *(const half8*)&wth[(2 * 64 + t * 16 + lr) * 72 + ks * 32 + kg * 8];
                    c = __builtin_amdgcn_mfma_f32_16x16x32_f16(af[ks], bf, c, 0, 0, 0);
                }
                const float bias = bv[t * 16 + lr];
                #pragma unroll
                for (int r = 0; r < 4; ++r) cv[t][r] = c[r] + bias;
            }
            #pragma unroll
            for (int r = 0; r < 4; ++r) {
                float amax = fmaxf(fmaxf(fabsf(cv[0][r]), fabsf(cv[1][r])),
                                   fmaxf(fabsf(cv[2][r]), fabsf(cv[3][r])));
                amax = fmaxf(amax, __shfl_xor(amax, 1));
                amax = fmaxf(amax, __shfl_xor(amax, 2));
                amax = fmaxf(amax, __shfl_xor(amax, 4));
                amax = fmaxf(amax, __shfl_xor(amax, 8));
                const int n = nb + kg * 4 + r;
                const float sinv = (amax > 0.f) ? 127.f / amax : 0.f;
                #pragma unroll
                for (int t = 0; t < 4; ++t)
                    kvtab[(size_t)n * 128 + 64 + t * 16 + lr] =
                        (signed char)__float2int_rn(cv[t][r] * sinv);
                if (lr == 0) vscale[n] = amax * (1.f / 127.f);
            }
        }
    }
}

// ---------------------------------------------------------------------------
// Gather + attention + Wo projection + residual. R9 frame; per pair ONE
// random 128B kvtab line (k bytes 0..63, v bytes 64..127) + L2-resident
// vscale broadcast. 1M random lines instead of 2M.
// ---------------------------------------------------------------------------
__device__ __forceinline__ void pair_accum(
    unsigned pk, unsigned kk, unsigned vq, float vs, const __half* npos_s, int cc,
    const float4& a4, const float4& a4s, float4& ac)
{
    const int kidx = (int)(pk & 127u);
    const __half2* np = (const __half2*)&npos_s[kidx * 64 + cc];
    const float2 c01 = __half22float2(np[0]);
    const float2 c23 = __half22float2(np[1]);
    const int ki = (int)kk;
    const float k0 = (float)(signed char)(ki);
    const float k1 = (float)(signed char)(ki >> 8);
    const float k2 = (float)(signed char)(ki >> 16);
    const float k3 = (float)(ki >> 24);
    float pdot = a4s.x * k0 + a4s.y * k1 + a4s.z * k2 + a4s.w * k3
               + a4.x * c01.x + a4.y * c01.y + a4.z * c23.x + a4.w * c23.y;
    pdot += __shfl_xor(pdot, 1);
    pdot += __shfl_xor(pdot, 2);
    const float w = pdot * vs;
    const int vi = (int)vq;
    ac.x += w * (float)(signed char)(vi);
    ac.y += w * (float)(signed char)(vi >> 8);
    ac.z += w * (float)(signed char)(vi >> 16);
    ac.w += w * (float)(vi >> 24);
}

__device__ __forceinline__ void quad_accum(
    uint4 u, const signed char* __restrict__ kvtab, const float* __restrict__ vscale,
    const __half* npos_s, int cc, const float4& a4, const float4& a4s, float4& ac)
{
    const signed char* r0 = kvtab + (size_t)(u.x >> 7) * 128;
    const signed char* r1 = kvtab + (size_t)(u.y >> 7) * 128;
    const signed char* r2 = kvtab + (size_t)(u.z >> 7) * 128;
    const signed char* r3 = kvtab + (size_t)(u.w >> 7) * 128;
    const unsigned kk0 = *(const unsigned*)(r0 + cc);
    const unsigned kk1 = *(const unsigned*)(r1 + cc);
    const unsigned kk2 = *(const unsigned*)(r2 + cc);
    const unsigned kk3 = *(const unsigned*)(r3 + cc);
    const unsigned vq0 = *(const unsigned*)(r0 + 64 + cc);
    const unsigned vq1 = *(const unsigned*)(r1 + 64 + cc);
    const unsigned vq2 = *(const unsigned*)(r2 + 64 + cc);
    const unsigned vq3 = *(const unsigned*)(r3 + 64 + cc);
    const float vs0 = vscale[u.x >> 7];
    const float vs1 = vscale[u.y >> 7];
    const float vs2 = vscale[u.z >> 7];
    const float vs3 = vscale[u.w >> 7];
    pair_accum(u.x, kk0, vq0, vs0, npos_s, cc, a4, a4s, ac);
    pair_accum(u.y, kk1, vq1, vs1, npos_s, cc, a4, a4s, ac);
    pair_accum(u.z, kk2, vq2, vs2, npos_s, cc, a4, a4s, ac);
    pair_accum(u.w, kk3, vq3, vs3, npos_s, cc, a4, a4s, ac);
}

__device__ __forceinline__ void tail_accum(
    uint4 u, int r, const signed char* __restrict__ kvtab, const float* __restrict__ vscale,
    const __half* npos_s, int cc, const float4& a4, const float4& a4s, float4& ac)
{
    if (r > 0) {
        const signed char* rp = kvtab + (size_t)(u.x >> 7) * 128;
        pair_accum(u.x, *(const unsigned*)(rp + cc), *(const unsigned*)(rp + 64 + cc),
                   vscale[u.x >> 7], npos_s, cc, a4, a4s, ac);
    }
    if (r > 1) {
        const signed char* rp = kvtab + (size_t)(u.y >> 7) * 128;
        pair_accum(u.y, *(const unsigned*)(rp + cc), *(const unsigned*)(rp + 64 + cc),
                   vscale[u.y >> 7], npos_s, cc, a4, a4s, ac);
    }
    if (r > 2) {
        const signed char* rp = kvtab + (size_t)(u.z >> 7) * 128;
        pair_accum(u.z, *(const unsigned*)(rp + cc), *(const unsigned*)(rp + 64 + cc),
                   vscale[u.z >> 7], npos_s, cc, a4, a4s, ac);
    }
}

__global__ __launch_bounds__(256, 4) void gather_out_kernel(
    const int* __restrict__ cursor, const unsigned int* __restrict__ pairlist,
    const __half* __restrict__ nqh, const signed char* __restrict__ kvtab,
    const float* __restrict__ vscale, const __half* __restrict__ nposh,
    const float* __restrict__ Wo, const float* __restrict__ bo,
    const float* __restrict__ x, float* __restrict__ out)
{
    __shared__ float wo_s[4096];
    __shared__ __half npos_s[8192];
    __shared__ float ms[4][4][64];
    const int tid = threadIdx.x;
    for (int i = tid; i < 1024; i += 256) ((float4*)wo_s)[i] = ((const float4*)Wo)[i];
    for (int i = tid; i < 1000; i += 256) ((uint4*)npos_s)[i] = ((const uint4*)nposh)[i];
    __syncthreads();

    const int lane = tid & 63;
    const int wid  = tid >> 6;
    const int l    = lane & 15;
    const int pg   = lane >> 4;
    const int cc   = l * 4;
    const int gw   = blockIdx.x * 4 + wid;   // 4096 waves
    const float4 bo4 = *(const float4*)&bo[cc];

    for (int nb = gw * 4; nb < NVOX; nb += GATH_BLOCKS * 16) {
        // ---- pair phase: 4 voxels, register accumulation ----
        #pragma unroll
        for (int v = 0; v < 4; ++v) {
            const int n = nb + v;
            const uint2 qp = *(const uint2*)(nqh + (size_t)n * 64 + cc);
            const float2 q01 = __half22float2(*(const __half2*)&qp.x);
            const float2 q23 = __half22float2(*(const __half2*)&qp.y);
            const float4 a4 = make_float4(q01.x, q01.y, q23.x, q23.y);
            const float4 a4s = make_float4(a4.x * (1.f / 127.f), a4.y * (1.f / 127.f),
                                           a4.z * (1.f / 127.f), a4.w * (1.f / 127.f));
            const int cnt = min(cursor[n], CAP);
            const int m = (cnt > pg) ? ((cnt - pg + 3) >> 2) : 0;
            const uint4* pb = (const uint4*)(pairlist + (size_t)n * CAP + pg * 12);
            const uint4 u0 = pb[0];
            const uint4 u1 = pb[1];
            const uint4 u2 = pb[2];
            float4 acc = make_float4(0.f, 0.f, 0.f, 0.f);
            int rem = m;
            if (rem >= 4) { quad_accum(u0, kvtab, vscale, npos_s, cc, a4, a4s, acc); rem -= 4; }
            else          { tail_accum(u0, rem, kvtab, vscale, npos_s, cc, a4, a4s, acc); rem = 0; }
            if (rem >= 4) { quad_accum(u1, kvtab, vscale, npos_s, cc, a4, a4s, acc); rem -= 4; }
            else if (rem > 0) { tail_accum(u1, rem, kvtab, vscale, npos_s, cc, a4, a4s, acc); rem = 0; }
            if (rem >= 4) { quad_accum(u2, kvtab, vscale, npos_s, cc, a4, a4s, acc); rem -= 4; }
            else if (rem > 0) { tail_accum(u2, rem, kvtab, vscale, npos_s, cc, a4, a4s, acc); rem = 0; }
            acc.x += __shfl_xor(acc.x, 16); acc.y += __shfl_xor(acc.y, 16);
            acc.z += __shfl_xor(acc.z, 16); acc.w += __shfl_xor(acc.w, 16);
            acc.x += __shfl_xor(acc.x, 32); acc.y += __shfl_xor(acc.y, 32);
            acc.z += __shfl_xor(acc.z, 32); acc.w += __shfl_xor(acc.w, 32);
            if (pg == 0) *(float4*)&ms[wid][v][cc] = acc;
        }
        __syncthreads();
        // ---- epilogue: out = msg @ Wo + bo + x  (j split across quarters) ----
        float4 o4[4];
        #pragma unroll
        for (int v = 0; v < 4; ++v) o4[v] = make_float4(0.f, 0.f, 0.f, 0.f);
        #pragma unroll
        for (int ib = 0; ib < 4; ++ib) {
            float4 mq[4];
            #pragma unroll
            for (int v = 0; v < 4; ++v)
                mq[v] = *(const float4*)&ms[wid][v][pg * 16 + ib * 4];
            #pragma unroll
            for (int tt = 0; tt < 4; ++tt) {
                const int j = pg * 16 + ib * 4 + tt;
                const float4 w4 = *(const float4*)&wo_s[j * 64 + cc];
                #pragma unroll
                for (int v = 0; v < 4; ++v) {
                    const float m = (tt == 0 ? mq[v].x : tt == 1 ? mq[v].y :
                                     tt == 2 ? mq[v].z : mq[v].w);
                    o4[v].x += m * w4.x; o4[v].y += m * w4.y;
                    o4[v].z += m * w4.z; o4[v].w += m * w4.w;
                }
            }
        }
        #pragma unroll
        for (int v = 0; v < 4; ++v) {
            o4[v].x += __shfl_xor(o4[v].x, 16); o4[v].y += __shfl_xor(o4[v].y, 16);
            o4[v].z += __shfl_xor(o4[v].z, 16); o4[v].w += __shfl_xor(o4[v].w, 16);
            o4[v].x += __shfl_xor(o4[v].x, 32); o4[v].y += __shfl_xor(o4[v].y, 32);
            o4[v].z += __shfl_xor(o4[v].z, 32); o4[v].w += __shfl_xor(o4[v].w, 32);
        }
        if (pg == 0) {
            #pragma unroll
            for (int v = 0; v < 4; ++v) {
                const float4 xr = *(const float4*)&x[(size_t)(nb + v) * 64 + cc];
                float4 r;
                r.x = o4[v].x + bo4.x + xr.x;
                r.y = o4[v].y + bo4.y + xr.y;
                r.z = o4[v].z + bo4.z + xr.z;
                r.w = o4[v].w + bo4.w + xr.w;
                *(float4*)&out[(size_t)(nb + v) * 64 + cc] = r;
            }
        }
        __syncthreads();
    }
}

// ---------------------------------------------------------------------------
extern "C" void kernel_launch(void* const* d_in, const int* in_sizes, int n_in,
                              void* d_out, int out_size, void* d_ws, size_t ws_size,
                              hipStream_t stream) {
    const float* x   = (const float*)d_in[0];
    const float* Wq  = (const float*)d_in[1];
    const float* bq  = (const float*)d_in[2];
    const float* Wk  = (const float*)d_in[3];
    const float* bk  = (const float*)d_in[4];
    const float* Wv  = (const float*)d_in[5];
    const float* bv  = (const float*)d_in[6];
    const float* Wo  = (const float*)d_in[7];
    const float* bo  = (const float*)d_in[8];
    const float* pos = (const float*)d_in[9];
    const int*   kq  = (const int*)d_in[10];

    char* w = (char*)d_ws;
    __half*       nqh      = (__half*)w;       w += (size_t)NVOX * 64 * 2;    // 8 MB
    signed char*  kvtab    = (signed char*)w;  w += (size_t)NVOX * 128;       // 8 MB
    unsigned int* pairlist = (unsigned int*)w; w += (size_t)NVOX * CAP * 4;   // 12 MB
    int*          cursor   = (int*)w;          w += (size_t)NVOX * 4;         // 256 KB
    float*        vscale   = (float*)w;        w += (size_t)NVOX * 4;         // 256 KB
    __half*       nposh    = (__half*)w;       w += 16384;                    // 16 KB

    zero_cursor_kernel<<<64, 256, 0, stream>>>((int4*)cursor);
    qkv_fill_kernel<<<MERGED_BLOCKS, 256, 0, stream>>>(x, Wq, bq, Wk, bk, Wv, bv,
                                                       nqh, kvtab, vscale,
                                                       pos, kq, nposh, cursor, pairlist);
    gather_out_kernel<<<GATH_BLOCKS, 256, 0, stream>>>(cursor, pairlist, nqh, kvtab,
                                                       vscale, nposh, Wo, bo, x,
                                                       (float*)d_out);
}

// Round 14
// 220.631 us; speedup vs baseline: 3.0923x; 1.0060x over previous
//
#include <hip/hip_runtime.h>
#include <hip/hip_fp16.h>

#define NVOX 65536
#define KVOL 125
#define NPAIR 1048576
#define CAP 48            // per-voxel bin capacity; counts ~ Poisson(16)
#define CSTRIDE 16        // cursor padded to 1 counter per 64B line (contention fix)
#define QKV_BLOCKS 1024
#define FILL_BLOCKS 2048
#define MERGED_BLOCKS (QKV_BLOCKS + FILL_BLOCKS)   // 3072 = 256 groups * 12
#define GATH_BLOCKS 1024   // R6: more gather concurrency = L2 thrash; R11: coop/grid.sync dead

typedef _Float16 half8 __attribute__((ext_vector_type(8)));
typedef float f32x4 __attribute__((ext_vector_type(4)));

// ---------------------------------------------------------------------------
// cursor zeroing: 4 MB padded table (must precede fill-role atomics)
// ---------------------------------------------------------------------------
__global__ __launch_bounds__(256) void zero_cursor_kernel(int4* __restrict__ c4)
{
    c4[blockIdx.x * 256 + threadIdx.x] = make_int4(0, 0, 0, 0);
}

// ---------------------------------------------------------------------------
// FUSED qkv + fill — R13 structure. R14: (1) cursor atomics padded to one
// counter per 64B line: same atomic count but <=16 tickets/line (was ~256),
// killing line-serialization + cross-XCD line ping-pong (~55MB of RMW line
// traffic in R13's WRITE_SIZE). (2) qkv role 768->1024 blocks: exactly 1
// MFMA tile per wave (was 1.33 -> straggler tail).
// ---------------------------------------------------------------------------
__global__ __launch_bounds__(256, 3) void qkv_fill_kernel(
    const float* __restrict__ x,
    const float* __restrict__ Wq, const float* __restrict__ bq,
    const float* __restrict__ Wk, const float* __restrict__ bk,
    const float* __restrict__ Wv, const float* __restrict__ bv,
    __half* __restrict__ nqh, signed char* __restrict__ kvtab,
    float* __restrict__ vscale,
    const float* __restrict__ pos, const int* __restrict__ kq_map,
    __half* __restrict__ nposh, int* __restrict__ cursor,
    unsigned int* __restrict__ pairlist)
{
    __shared__ _Float16 wth[3 * 64 * 72];   // qkv role only: W^T fp16 [m][c][k]
    const int tid  = threadIdx.x;
    const int lane = tid & 63;
    const int wid  = tid >> 6;
    const int grp  = blockIdx.x / 12;
    const int sub  = blockIdx.x - grp * 12;

    if (sub >= 4) {
        // ---------------- fill role (block id fb in [0, 2048)) ----------------
        const int fb = grp * 8 + (sub - 4);
        if (fb < KVOL && wid == 0) {
            const float pv = pos[fb * 64 + lane];
            float s = pv * pv;
            #pragma unroll
            for (int m = 1; m <= 8; m <<= 1) s += __shfl_xor(s, m);
            nposh[fb * 64 + lane] = __float2half(pv / fmaxf(sqrtf(s), 1e-12f));
        }
        const int gtid = fb * 256 + tid;            // 0..524287
        const int p0 = gtid;
        const int p1 = gtid + 524288;
        const unsigned k0 = (unsigned)kq_map[p0];
        const unsigned k1 = (unsigned)kq_map[p1];
        const int o0 = kq_map[NPAIR + p0];
        const int o1 = kq_map[NPAIR + p1];
        const int r0 = atomicAdd(&cursor[o0 * CSTRIDE], 1);
        const int r1 = atomicAdd(&cursor[o1 * CSTRIDE], 1);
        const unsigned i0 = k0 / 125u, i1 = k1 / 125u;
        // permuted slot: group-major layout for uint4 gather reads
        if (r0 < CAP) pairlist[(size_t)o0 * CAP + ((r0 & 3) * 12 + (r0 >> 2))]
                        = (i0 << 7) | (k0 - i0 * 125u);
        if (r1 < CAP) pairlist[(size_t)o1 * CAP + ((r1 & 3) * 12 + (r1 >> 2))]
                        = (i1 << 7) | (k1 - i1 * 125u);
        return;
    }

    // ---------------- qkv role (block id qb in [0, 1024)) ----------------
    const int qb = grp * 4 + sub;
    for (int idx = tid; idx < 3 * 4096; idx += 256) {
        const int m = idx >> 12;
        const int r = idx & 4095;
        const int k = r >> 6;      // input channel (W row)
        const int c = r & 63;      // output channel (W col)
        const float wv = (m == 0 ? Wq : (m == 1 ? Wk : Wv))[k * 64 + c];
        wth[(m * 64 + c) * 72 + k] = (_Float16)wv;
    }
    __syncthreads();

    const int lr = lane & 15;   // A-row / C-col / B-col
    const int kg = lane >> 4;   // k-group of 8
    const int nb = (qb * 4 + wid) << 4;   // 4096 waves x exactly 1 tile of 16 voxels

    {
        half8 af[2];
        #pragma unroll
        for (int ks = 0; ks < 2; ++ks) {
            const float4 xa = *(const float4*)&x[(size_t)(nb + lr) * 64 + ks * 32 + kg * 8];
            const float4 xb = *(const float4*)&x[(size_t)(nb + lr) * 64 + ks * 32 + kg * 8 + 4];
            half8 t;
            t[0] = (_Float16)xa.x; t[1] = (_Float16)xa.y;
            t[2] = (_Float16)xa.z; t[3] = (_Float16)xa.w;
            t[4] = (_Float16)xb.x; t[5] = (_Float16)xb.y;
            t[6] = (_Float16)xb.z; t[7] = (_Float16)xb.w;
            af[ks] = t;
        }
        // ---- q and k: project, L2-normalize per head, store ----
        #pragma unroll
        for (int m = 0; m < 2; ++m) {
            const float* bp = (m == 0 ? bq : bk);
            #pragma unroll
            for (int t = 0; t < 4; ++t) {        // head / 16-col output tile
                f32x4 c = {0.f, 0.f, 0.f, 0.f};
                #pragma unroll
                for (int ks = 0; ks < 2; ++ks) {
                    const half8 bf = *(const half8*)&wth[(m * 64 + t * 16 + lr) * 72 + ks * 32 + kg * 8];
                    c = __builtin_amdgcn_mfma_f32_16x16x32_f16(af[ks], bf, c, 0, 0, 0);
                }
                const float bias = bp[t * 16 + lr];
                #pragma unroll
                for (int r = 0; r < 4; ++r) {
                    const float av = c[r] + bias;
                    float s = av * av;
                    s += __shfl_xor(s, 1); s += __shfl_xor(s, 2);
                    s += __shfl_xor(s, 4); s += __shfl_xor(s, 8);
                    const float inv = av / fmaxf(sqrtf(s), 1e-12f);
                    const int n = nb + kg * 4 + r;
                    if (m == 0) nqh[(size_t)n * 64 + t * 16 + lr] = __float2half(inv);
                    else        kvtab[(size_t)n * 128 + t * 16 + lr] =
                                    (signed char)__float2int_rn(inv * 127.f);
                }
            }
        }
        // ---- v: project all 4 tiles, per-voxel-row int8 quantization ----
        {
            f32x4 cv[4];
            #pragma unroll
            for (int t = 0; t < 4; ++t) {
                f32x4 c = {0.f, 0.f, 0.f, 0.f};
                #pragma unroll
                for (int ks = 0; ks < 2; ++ks) {
                    const half8 bf = *(const half8*)&wth[(2 * 64 + t * 16 + lr) * 72 + ks * 32 + kg * 8];
                    c = __builtin_amdgcn_mfma_f32_16x16x32_f16(af[ks], bf, c, 0, 0, 0);
                }
                const float bias = bv[t * 16 + lr];
                #pragma unroll
                for (int r = 0; r < 4; ++r) cv[t][r] = c[r] + bias;
            }
            #pragma unroll
            for (int r = 0; r < 4; ++r) {
                float amax = fmaxf(fmaxf(fabsf(cv[0][r]), fabsf(cv[1][r])),
                                   fmaxf(fabsf(cv[2][r]), fabsf(cv[3][r])));
                amax = fmaxf(amax, __shfl_xor(amax, 1));
                amax = fmaxf(amax, __shfl_xor(amax, 2));
                amax = fmaxf(amax, __shfl_xor(amax, 4));
                amax = fmaxf(amax, __shfl_xor(amax, 8));
                const int n = nb + kg * 4 + r;
                const float sinv = (amax > 0.f) ? 127.f / amax : 0.f;
                #pragma unroll
                for (int t = 0; t < 4; ++t)
                    kvtab[(size_t)n * 128 + 64 + t * 16 + lr] =
                        (signed char)__float2int_rn(cv[t][r] * sinv);
                if (lr == 0) vscale[n] = amax * (1.f / 127.f);
            }
        }
    }
}

// ---------------------------------------------------------------------------
// Gather + attention + Wo projection + residual. R13 frame; per pair ONE
// random 128B kvtab line (k bytes 0..63, v bytes 64..127) + L2-resident
// vscale broadcast. cursor read at padded stride.
// ---------------------------------------------------------------------------
__device__ __forceinline__ void pair_accum(
    unsigned pk, unsigned kk, unsigned vq, float vs, const __half* npos_s, int cc,
    const float4& a4, const float4& a4s, float4& ac)
{
    const int kidx = (int)(pk & 127u);
    const __half2* np = (const __half2*)&npos_s[kidx * 64 + cc];
    const float2 c01 = __half22float2(np[0]);
    const float2 c23 = __half22float2(np[1]);
    const int ki = (int)kk;
    const float k0 = (float)(signed char)(ki);
    const float k1 = (float)(signed char)(ki >> 8);
    const float k2 = (float)(signed char)(ki >> 16);
    const float k3 = (float)(ki >> 24);
    float pdot = a4s.x * k0 + a4s.y * k1 + a4s.z * k2 + a4s.w * k3
               + a4.x * c01.x + a4.y * c01.y + a4.z * c23.x + a4.w * c23.y;
    pdot += __shfl_xor(pdot, 1);
    pdot += __shfl_xor(pdot, 2);
    const float w = pdot * vs;
    const int vi = (int)vq;
    ac.x += w * (float)(signed char)(vi);
    ac.y += w * (float)(signed char)(vi >> 8);
    ac.z += w * (float)(signed char)(vi >> 16);
    ac.w += w * (float)(vi >> 24);
}

__device__ __forceinline__ void quad_accum(
    uint4 u, const signed char* __restrict__ kvtab, const float* __restrict__ vscale,
    const __half* npos_s, int cc, const float4& a4, const float4& a4s, float4& ac)
{
    const signed char* r0 = kvtab + (size_t)(u.x >> 7) * 128;
    const signed char* r1 = kvtab + (size_t)(u.y >> 7) * 128;
    const signed char* r2 = kvtab + (size_t)(u.z >> 7) * 128;
    const signed char* r3 = kvtab + (size_t)(u.w >> 7) * 128;
    const unsigned kk0 = *(const unsigned*)(r0 + cc);
    const unsigned kk1 = *(const unsigned*)(r1 + cc);
    const unsigned kk2 = *(const unsigned*)(r2 + cc);
    const unsigned kk3 = *(const unsigned*)(r3 + cc);
    const unsigned vq0 = *(const unsigned*)(r0 + 64 + cc);
    const unsigned vq1 = *(const unsigned*)(r1 + 64 + cc);
    const unsigned vq2 = *(const unsigned*)(r2 + 64 + cc);
    const unsigned vq3 = *(const unsigned*)(r3 + 64 + cc);
    const float vs0 = vscale[u.x >> 7];
    const float vs1 = vscale[u.y >> 7];
    const float vs2 = vscale[u.z >> 7];
    const float vs3 = vscale[u.w >> 7];
    pair_accum(u.x, kk0, vq0, vs0, npos_s, cc, a4, a4s, ac);
    pair_accum(u.y, kk1, vq1, vs1, npos_s, cc, a4, a4s, ac);
    pair_accum(u.z, kk2, vq2, vs2, npos_s, cc, a4, a4s, ac);
    pair_accum(u.w, kk3, vq3, vs3, npos_s, cc, a4, a4s, ac);
}

__device__ __forceinline__ void tail_accum(
    uint4 u, int r, const signed char* __restrict__ kvtab, const float* __restrict__ vscale,
    const __half* npos_s, int cc, const float4& a4, const float4& a4s, float4& ac)
{
    if (r > 0) {
        const signed char* rp = kvtab + (size_t)(u.x >> 7) * 128;
        pair_accum(u.x, *(const unsigned*)(rp + cc), *(const unsigned*)(rp + 64 + cc),
                   vscale[u.x >> 7], npos_s, cc, a4, a4s, ac);
    }
    if (r > 1) {
        const signed char* rp = kvtab + (size_t)(u.y >> 7) * 128;
        pair_accum(u.y, *(const unsigned*)(rp + cc), *(const unsigned*)(rp + 64 + cc),
                   vscale[u.y >> 7], npos_s, cc, a4, a4s, ac);
    }
    if (r > 2) {
        const signed char* rp = kvtab + (size_t)(u.z >> 7) * 128;
        pair_accum(u.z, *(const unsigned*)(rp + cc), *(const unsigned*)(rp + 64 + cc),
                   vscale[u.z >> 7], npos_s, cc, a4, a4s, ac);
    }
}

__global__ __launch_bounds__(256, 4) void gather_out_kernel(
    const int* __restrict__ cursor, const unsigned int* __restrict__ pairlist,
    const __half* __restrict__ nqh, const signed char* __restrict__ kvtab,
    const float* __restrict__ vscale, const __half* __restrict__ nposh,
    const float* __restrict__ Wo, const float* __restrict__ bo,
    const float* __restrict__ x, float* __restrict__ out)
{
    __shared__ float wo_s[4096];
    __shared__ __half npos_s[8192];
    __shared__ float ms[4][4][64];
    const int tid = threadIdx.x;
    for (int i = tid; i < 1024; i += 256) ((float4*)wo_s)[i] = ((const float4*)Wo)[i];
    for (int i = tid; i < 1000; i += 256) ((uint4*)npos_s)[i] = ((const uint4*)nposh)[i];
    __syncthreads();

    const int lane = tid & 63;
    const int wid  = tid >> 6;
    const int l    = lane & 15;
    const int pg   = lane >> 4;
    const int cc   = l * 4;
    const int gw   = blockIdx.x * 4 + wid;   // 4096 waves
    const float4 bo4 = *(const float4*)&bo[cc];

    for (int nb = gw * 4; nb < NVOX; nb += GATH_BLOCKS * 16) {
        // ---- pair phase: 4 voxels, register accumulation ----
        #pragma unroll
        for (int v = 0; v < 4; ++v) {
            const int n = nb + v;
            const uint2 qp = *(const uint2*)(nqh + (size_t)n * 64 + cc);
            const float2 q01 = __half22float2(*(const __half2*)&qp.x);
            const float2 q23 = __half22float2(*(const __half2*)&qp.y);
            const float4 a4 = make_float4(q01.x, q01.y, q23.x, q23.y);
            const float4 a4s = make_float4(a4.x * (1.f / 127.f), a4.y * (1.f / 127.f),
                                           a4.z * (1.f / 127.f), a4.w * (1.f / 127.f));
            const int cnt = min(cursor[n * CSTRIDE], CAP);
            const int m = (cnt > pg) ? ((cnt - pg + 3) >> 2) : 0;
            const uint4* pb = (const uint4*)(pairlist + (size_t)n * CAP + pg * 12);
            const uint4 u0 = pb[0];
            const uint4 u1 = pb[1];
            const uint4 u2 = pb[2];
            float4 acc = make_float4(0.f, 0.f, 0.f, 0.f);
            int rem = m;
            if (rem >= 4) { quad_accum(u0, kvtab, vscale, npos_s, cc, a4, a4s, acc); rem -= 4; }
            else          { tail_accum(u0, rem, kvtab, vscale, npos_s, cc, a4, a4s, acc); rem = 0; }
            if (rem >= 4) { quad_accum(u1, kvtab, vscale, npos_s, cc, a4, a4s, acc); rem -= 4; }
            else if (rem > 0) { tail_accum(u1, rem, kvtab, vscale, npos_s, cc, a4, a4s, acc); rem = 0; }
            if (rem >= 4) { quad_accum(u2, kvtab, vscale, npos_s, cc, a4, a4s, acc); rem -= 4; }
            else if (rem > 0) { tail_accum(u2, rem, kvtab, vscale, npos_s, cc, a4, a4s, acc); rem = 0; }
            acc.x += __shfl_xor(acc.x, 16); acc.y += __shfl_xor(acc.y, 16);
            acc.z += __shfl_xor(acc.z, 16); acc.w += __shfl_xor(acc.w, 16);
            acc.x += __shfl_xor(acc.x, 32); acc.y += __shfl_xor(acc.y, 32);
            acc.z += __shfl_xor(acc.z, 32); acc.w += __shfl_xor(acc.w, 32);
            if (pg == 0) *(float4*)&ms[wid][v][cc] = acc;
        }
        __syncthreads();
        // ---- epilogue: out = msg @ Wo + bo + x  (j split across quarters) ----
        float4 o4[4];
        #pragma unroll
        for (int v = 0; v < 4; ++v) o4[v] = make_float4(0.f, 0.f, 0.f, 0.f);
        #pragma unroll
        for (int ib = 0; ib < 4; ++ib) {
            float4 mq[4];
            #pragma unroll
            for (int v = 0; v < 4; ++v)
                mq[v] = *(const float4*)&ms[wid][v][pg * 16 + ib * 4];
            #pragma unroll
            for (int tt = 0; tt < 4; ++tt) {
                const int j = pg * 16 + ib * 4 + tt;
                const float4 w4 = *(const float4*)&wo_s[j * 64 + cc];
                #pragma unroll
                for (int v = 0; v < 4; ++v) {
                    const float m = (tt == 0 ? mq[v].x : tt == 1 ? mq[v].y :
                                     tt == 2 ? mq[v].z : mq[v].w);
                    o4[v].x += m * w4.x; o4[v].y += m * w4.y;
                    o4[v].z += m * w4.z; o4[v].w += m * w4.w;
                }
            }
        }
        #pragma unroll
        for (int v = 0; v < 4; ++v) {
            o4[v].x += __shfl_xor(o4[v].x, 16); o4[v].y += __shfl_xor(o4[v].y, 16);
            o4[v].z += __shfl_xor(o4[v].z, 16); o4[v].w += __shfl_xor(o4[v].w, 16);
            o4[v].x += __shfl_xor(o4[v].x, 32); o4[v].y += __shfl_xor(o4[v].y, 32);
            o4[v].z += __shfl_xor(o4[v].z, 32); o4[v].w += __shfl_xor(o4[v].w, 32);
        }
        if (pg == 0) {
            #pragma unroll
            for (int v = 0; v < 4; ++v) {
                const float4 xr = *(const float4*)&x[(size_t)(nb + v) * 64 + cc];
                float4 r;
                r.x = o4[v].x + bo4.x + xr.x;
                r.y = o4[v].y + bo4.y + xr.y;
                r.z = o4[v].z + bo4.z + xr.z;
                r.w = o4[v].w + bo4.w + xr.w;
                *(float4*)&out[(size_t)(nb + v) * 64 + cc] = r;
            }
        }
        __syncthreads();
    }
}

// ---------------------------------------------------------------------------
extern "C" void kernel_launch(void* const* d_in, const int* in_sizes, int n_in,
                              void* d_out, int out_size, void* d_ws, size_t ws_size,
                              hipStream_t stream) {
    const float* x   = (const float*)d_in[0];
    const float* Wq  = (const float*)d_in[1];
    const float* bq  = (const float*)d_in[2];
    const float* Wk  = (const float*)d_in[3];
    const float* bk  = (const float*)d_in[4];
    const float* Wv  = (const float*)d_in[5];
    const float* bv  = (const float*)d_in[6];
    const float* Wo  = (const float*)d_in[7];
    const float* bo  = (const float*)d_in[8];
    const float* pos = (const float*)d_in[9];
    const int*   kq  = (const int*)d_in[10];

    char* w = (char*)d_ws;
    __half*       nqh      = (__half*)w;       w += (size_t)NVOX * 64 * 2;        // 8 MB
    signed char*  kvtab    = (signed char*)w;  w += (size_t)NVOX * 128;           // 8 MB
    unsigned int* pairlist = (unsigned int*)w; w += (size_t)NVOX * CAP * 4;       // 12 MB
    int*          cursor   = (int*)w;          w += (size_t)NVOX * CSTRIDE * 4;   // 4 MB
    float*        vscale   = (float*)w;        w += (size_t)NVOX * 4;             // 256 KB
    __half*       nposh    = (__half*)w;       w += 16384;                        // 16 KB

    zero_cursor_kernel<<<NVOX * CSTRIDE / 1024, 256, 0, stream>>>((int4*)cursor);
    qkv_fill_kernel<<<MERGED_BLOCKS, 256, 0, stream>>>(x, Wq, bq, Wk, bk, Wv, bv,
                                                       nqh, kvtab, vscale,
                                                       pos, kq, nposh, cursor, pairlist);
    gather_out_kernel<<<GATH_BLOCKS, 256, 0, stream>>>(cursor, pairlist, nqh, kvtab,
                                                       vscale, nposh, Wo, bo, x,
                                                       (float*)d_out);
}